// Round 2
// baseline (116.955 us; speedup 1.0000x reference)
//
#include <hip/hip_runtime.h>

// TwoRobots: x1 = x + (A1x + A2x + Bu)*H + w, elementwise over B=1e6 columns.
// Trig identities collapse: Fgx = -KS*dx - CD*vx ; Fgy = -KS*dy - CD*vy.
// Memory-bound: 112 B/column -> ~18 us floor at 6.3 TB/s.
// R1: agents split across blockIdx.y -> 14 streams/thread (was 28), 2x waves.

#define H_STEP 0.05f
#define KSC    2.0f
#define CDC    2.0f

__global__ __launch_bounds__(256)
void two_robots_kernel(const float4* __restrict__ x4,
                       const float4* __restrict__ u4,
                       const float4* __restrict__ w4,
                       const float*  __restrict__ xbar,
                       float4* __restrict__ out4,
                       int nvec)  // nvec = B/4
{
    const int i = blockIdx.x * blockDim.x + threadIdx.x;
    if (i >= nvec) return;
    const int a = blockIdx.y;                  // agent 0 / 1 (wave-uniform)

    const float xt = xbar[a * 4 + 0];          // scalar loads (uniform)
    const float yt = xbar[a * 4 + 1];

    const size_t r0 = (size_t)(a * 4 + 0) * nvec + i;
    const size_t r1 = (size_t)(a * 4 + 1) * nvec + i;
    const size_t r2 = (size_t)(a * 4 + 2) * nvec + i;
    const size_t r3 = (size_t)(a * 4 + 3) * nvec + i;
    const size_t u0 = (size_t)(a * 2 + 0) * nvec + i;
    const size_t u1 = (size_t)(a * 2 + 1) * nvec + i;

    float4 px = x4[r0];
    float4 py = x4[r1];
    float4 vx = x4[r2];
    float4 vy = x4[r3];
    float4 ux = u4[u0];
    float4 uy = u4[u1];
    float4 w0 = w4[r0];
    float4 w1 = w4[r1];
    float4 w2 = w4[r2];
    float4 w3 = w4[r3];

    float4 o0, o1, o2, o3;
#define LANE(c)                                                                 \
    o0.c = px.c + vx.c * H_STEP + w0.c;                                         \
    o1.c = py.c + vy.c * H_STEP + w1.c;                                         \
    o2.c = vx.c + (-KSC * (px.c - xt) - CDC * vx.c + ux.c) * H_STEP + w2.c;     \
    o3.c = vy.c + (-KSC * (py.c - yt) - CDC * vy.c + uy.c) * H_STEP + w3.c;
    LANE(x) LANE(y) LANE(z) LANE(w)
#undef LANE

    out4[r0] = o0;
    out4[r1] = o1;
    out4[r2] = o2;
    out4[r3] = o3;
}

extern "C" void kernel_launch(void* const* d_in, const int* in_sizes, int n_in,
                              void* d_out, int out_size, void* d_ws, size_t ws_size,
                              hipStream_t stream) {
    const float* x    = (const float*)d_in[0];   // (8, B)
    const float* u    = (const float*)d_in[1];   // (4, B)
    const float* w    = (const float*)d_in[2];   // (8, B)
    const float* xbar = (const float*)d_in[3];   // (8,)
    // d_in[4] = t (unused)
    float* out = (float*)d_out;                  // (8, B)

    const int B = in_sizes[0] / 8;               // 1,000,000 (divisible by 4)
    const int nvec = B / 4;
    const int block = 256;
    dim3 grid((nvec + block - 1) / block, 2);    // y = agent

    two_robots_kernel<<<grid, block, 0, stream>>>(
        (const float4*)x, (const float4*)u, (const float4*)w, xbar,
        (float4*)out, nvec);
}